// Round 6
// baseline (84.826 us; speedup 1.0000x reference)
//
#include <hip/hip_runtime.h>

// Problem dims (fixed by reference)
#define Bb  8
#define Mm  4096
#define Nn  64
#define Ff  9
#define Ss  5
#define NRr 3

// Per-atom LDS record: 48 floats (192 B):
//  [0]=bc0 [1]=p0 [2]=bc1 [3]=p1 [4]=bc2 [5]=p2 [6,7]=pad   (bc = b*log2 e)
//  [8+f*4 .. 11+f*4] = A_f, ux, uy, uz   (A = a*|c|, u = c/|c|)
constexpr int REC = 48;
constexpr int MT  = 64;   // m per block (each lane handles m and m+32)
constexpr int STR = 195;  // LDS row stride (odd): dv reads 2/bank, free

__global__ __launch_bounds__(256, 2)
void HarmonicGenAMD_25786983645325_kernel(
    const float* __restrict__ dv,     // [B,M,N,3]
    const float* __restrict__ coef,   // [B,N,F,3]
    const int*   __restrict__ labels, // [B,N]
    const float* __restrict__ pa,
    const float* __restrict__ pb,
    const float* __restrict__ pp,
    float*       __restrict__ out)    // [B,M]
{
    __shared__ __align__(16) float dvs[MT * STR];    // 49920 B
    __shared__ __align__(16) float tabs[Nn * REC];   // 12288 B
    __shared__ float red[256];                       // 1024 B  -> 63.2 KB: 2 blk/CU

    const int tid = threadIdx.x;
    const int blk = blockIdx.x;        // 0..511
    const int b   = blk >> 6;
    const int m0  = (blk & 63) * MT;

    // ---- stage dv tile: 64 rows x 192 floats, coalesced global float4 ----
    const float* g = dv + ((size_t)b * Mm + m0) * (Nn * 3);
#pragma unroll
    for (int it = 0; it < 12; ++it) {
        const int i   = it * 1024 + tid * 4;     // 12288 floats
        const int row = i / 192;
        const int col = i - row * 192;
        const float4 v = *(const float4*)(g + row * 192 + col);
        float* d = &dvs[row * STR + col];
        d[0] = v.x; d[1] = v.y; d[2] = v.z; d[3] = v.w;
    }

    // ---- build atom table in LDS (overlaps staging loads) ----
    if (tid < Nn) {
        const int s = labels[b * Nn + tid];
        float4 h0, h1;
        h0.x = pb[s * NRr + 0] * 1.44269504088896340736f;  h0.y = pp[s * NRr + 0];
        h0.z = pb[s * NRr + 1] * 1.44269504088896340736f;  h0.w = pp[s * NRr + 1];
        h1.x = pb[s * NRr + 2] * 1.44269504088896340736f;  h1.y = pp[s * NRr + 2];
        h1.z = 0.0f; h1.w = 0.0f;
        *(float4*)(&tabs[tid * REC + 0]) = h0;
        *(float4*)(&tabs[tid * REC + 4]) = h1;
    }
    for (int i = tid; i < Nn * Ff; i += 256) {
        const int n = i / Ff;
        const int f = i - n * Ff;
        const int j = f / 3;
        const int s = labels[b * Nn + n];
        const float* c = coef + ((size_t)(b * Nn + n) * Ff + f) * 3;
        const float cx = c[0], cy = c[1], cz = c[2];
        const float cn  = sqrtf(cx * cx + cy * cy + cz * cz);
        const float inv = 1.0f / fmaxf(cn, 1e-12f);
        float4 q;
        q.x = pa[s * NRr + j] * cn;
        q.y = cx * inv; q.z = cy * inv; q.w = cz * inv;
        *(float4*)(&tabs[n * REC + 8 + f * 4]) = q;
    }
    __syncthreads();

    // ---- main loop: DS-only. lane = (half h, m-base). K=2: each lane does
    // (m, n_h) and (m+32, n_h) per iter -> 128 pairs per 10-b128 record read.
    const int lane = tid & 63;
    const int w    = tid >> 6;
    const int mb   = lane & 31;
    const int h    = lane >> 5;
    const float* dlo = &dvs[mb * STR];
    const float* dhi = &dvs[(mb + 32) * STR];

    float acc0 = 0.0f, acc1 = 0.0f;
#pragma unroll 2
    for (int t = 0; t < 8; ++t) {
        const int n = w * 16 + t * 2 + h;
        const float* rec = &tabs[n * REC];
        // pair 0: m = mb
        const float x0 = dlo[n * 3 + 0], y0 = dlo[n * 3 + 1], z0 = dlo[n * 3 + 2];
        // pair 1: m = mb + 32
        const float x1 = dhi[n * 3 + 0], y1 = dhi[n * 3 + 1], z1 = dhi[n * 3 + 2];

        const float r2a  = __fmaf_rn(x0, x0, __fmaf_rn(y0, y0, z0 * z0));
        const float r2b  = __fmaf_rn(x1, x1, __fmaf_rn(y1, y1, z1 * z1));
        const float ria  = __builtin_amdgcn_rsqf(r2a);
        const float rib  = __builtin_amdgcn_rsqf(r2b);
        const float ra   = r2a * ria;
        const float rb   = r2b * rib;
        const float la   = 0.5f * __builtin_amdgcn_logf(r2a);   // log2(r)
        const float lb   = 0.5f * __builtin_amdgcn_logf(r2b);
        const float ax = x0 * ria, ay = y0 * ria, az = z0 * ria;
        const float bx = x1 * rib, by = y1 * rib, bz = z1 * rib;

        const float4 h0 = *(const float4*)(rec);       // bc0,p0,bc1,p1
        const float2 h1 = *(const float2*)(rec + 4);   // bc2,p2
        float eka[3], ekb[3];
        eka[0] = __builtin_amdgcn_exp2f(__fmaf_rn(h0.y, la, -h0.x * ra));
        ekb[0] = __builtin_amdgcn_exp2f(__fmaf_rn(h0.y, lb, -h0.x * rb));
        eka[1] = __builtin_amdgcn_exp2f(__fmaf_rn(h0.w, la, -h0.z * ra));
        ekb[1] = __builtin_amdgcn_exp2f(__fmaf_rn(h0.w, lb, -h0.z * rb));
        eka[2] = __builtin_amdgcn_exp2f(__fmaf_rn(h1.y, la, -h1.x * ra));
        ekb[2] = __builtin_amdgcn_exp2f(__fmaf_rn(h1.y, lb, -h1.x * rb));
#pragma unroll
        for (int f = 0; f < Ff; ++f) {
            const float4 e = *(const float4*)(rec + 8 + f * 4);  // A, ux, uy, uz
            const float ca = __fmaf_rn(ax, e.y, __fmaf_rn(ay, e.z, az * e.w));
            const float cb = __fmaf_rn(bx, e.y, __fmaf_rn(by, e.z, bz * e.w));
            float qa, qb;
            if (f % 3 == 0)      { qa = ca;                               qb = cb; }
            else if (f % 3 == 1) { qa = __fmaf_rn(1.5f * ca, ca, -0.5f);  qb = __fmaf_rn(1.5f * cb, cb, -0.5f); }
            else                 { qa = ca * __fmaf_rn(2.5f * ca, ca, -1.5f);
                                   qb = cb * __fmaf_rn(2.5f * cb, cb, -1.5f); }
            const float Aek_a = e.x * eka[f / 3];
            const float Aek_b = e.x * ekb[f / 3];
            acc0 = __fmaf_rn(Aek_a, qa, acc0);
            acc1 = __fmaf_rn(Aek_b, qb, acc1);
        }
    }

    // ---- reduce: halves within wave (both halves cover same m for diff atoms) ----
    acc0 += __shfl_down(acc0, 32, 64);
    acc1 += __shfl_down(acc1, 32, 64);
    if (h == 0) {
        red[w * 64 + mb]      = acc0;   // m = mb
        red[w * 64 + 32 + mb] = acc1;   // m = mb + 32
    }
    __syncthreads();
    if (tid < MT) {
        out[(size_t)b * Mm + m0 + tid] =
            red[tid] + red[64 + tid] + red[128 + tid] + red[192 + tid];
    }
}

extern "C" void kernel_launch(void* const* d_in, const int* in_sizes, int n_in,
                              void* d_out, int out_size, void* d_ws, size_t ws_size,
                              hipStream_t stream) {
    const float* dv   = (const float*)d_in[0];
    const float* coef = (const float*)d_in[1];
    const int*   lab  = (const int*)d_in[2];
    const float* pa   = (const float*)d_in[3];
    const float* pb   = (const float*)d_in[4];
    const float* pp   = (const float*)d_in[5];
    float* out = (float*)d_out;

    dim3 grid(Bb * (Mm / MT));  // 512 blocks = 2/CU, single launch
    HarmonicGenAMD_25786983645325_kernel<<<grid, 256, 0, stream>>>(
        dv, coef, lab, pa, pb, pp, out);
}

// Round 7
// 84.382 us; speedup vs baseline: 1.0053x; 1.0053x over previous
//
#include <hip/hip_runtime.h>

// Problem dims (fixed by reference)
#define Bb  8
#define Mm  4096
#define Nn  64
#define Ff  9
#define Ss  5
#define NRr 3

// Per-atom LDS record: 48 floats (192 B):
//  [0]=bc0 [1]=p0 [2]=bc1 [3]=p1 [4]=bc2 [5]=p2 [6,7]=pad   (bc = b*log2 e)
//  [8+f*4 .. 11+f*4] = A_f, ux, uy, uz   (A = a*|c|, u = c/|c|)
constexpr int REC = 48;
constexpr int MT  = 64;   // m per block (each lane handles m and m+32)
constexpr int STR = 195;  // LDS row stride (odd): dv reads 2/bank, free

// 512 threads = 8 waves/block; 4 waves/EU -> 2 blocks/CU = 16 waves/CU
__global__ __launch_bounds__(512, 4)
void HarmonicGenAMD_25786983645325_kernel(
    const float* __restrict__ dv,     // [B,M,N,3]
    const float* __restrict__ coef,   // [B,N,F,3]
    const int*   __restrict__ labels, // [B,N]
    const float* __restrict__ pa,
    const float* __restrict__ pb,
    const float* __restrict__ pp,
    float*       __restrict__ out)    // [B,M]
{
    __shared__ __align__(16) float dvs[MT * STR];    // 49920 B
    __shared__ __align__(16) float tabs[Nn * REC];   // 12288 B
    __shared__ float red[512];                       // 2048 B  -> 62.8 KB: 2 blk/CU

    const int tid = threadIdx.x;
    const int blk = blockIdx.x;        // 0..511
    const int b   = blk >> 6;
    const int m0  = (blk & 63) * MT;

    // ---- stage dv tile: 64 rows x 192 floats, coalesced global float4 ----
    const float* g = dv + ((size_t)b * Mm + m0) * (Nn * 3);
#pragma unroll
    for (int it = 0; it < 6; ++it) {
        const int i   = it * 2048 + tid * 4;     // 12288 floats
        const int row = i / 192;
        const int col = i - row * 192;
        const float4 v = *(const float4*)(g + row * 192 + col);
        float* d = &dvs[row * STR + col];
        d[0] = v.x; d[1] = v.y; d[2] = v.z; d[3] = v.w;
    }

    // ---- build atom table in LDS (overlaps staging loads) ----
    if (tid < Nn) {
        const int s = labels[b * Nn + tid];
        float4 h0, h1;
        h0.x = pb[s * NRr + 0] * 1.44269504088896340736f;  h0.y = pp[s * NRr + 0];
        h0.z = pb[s * NRr + 1] * 1.44269504088896340736f;  h0.w = pp[s * NRr + 1];
        h1.x = pb[s * NRr + 2] * 1.44269504088896340736f;  h1.y = pp[s * NRr + 2];
        h1.z = 0.0f; h1.w = 0.0f;
        *(float4*)(&tabs[tid * REC + 0]) = h0;
        *(float4*)(&tabs[tid * REC + 4]) = h1;
    }
    for (int i = tid; i < Nn * Ff; i += 512) {
        const int n = i / Ff;
        const int f = i - n * Ff;
        const int j = f / 3;
        const int s = labels[b * Nn + n];
        const float* c = coef + ((size_t)(b * Nn + n) * Ff + f) * 3;
        const float cx = c[0], cy = c[1], cz = c[2];
        const float cn  = sqrtf(cx * cx + cy * cy + cz * cz);
        const float inv = 1.0f / fmaxf(cn, 1e-12f);
        float4 q;
        q.x = pa[s * NRr + j] * cn;
        q.y = cx * inv; q.z = cy * inv; q.w = cz * inv;
        *(float4*)(&tabs[n * REC + 8 + f * 4]) = q;
    }
    __syncthreads();

    // ---- main loop: DS-only. Wave w covers atoms [w*8, w*8+8) in 4 iters.
    // K=2: each lane does (mb, n) and (mb+32, n) -> one record read / 128 pairs.
    const int lane = tid & 63;
    const int w    = tid >> 6;         // 0..7
    const int mb   = lane & 31;
    const int h    = lane >> 5;
    const float* dlo = &dvs[mb * STR];
    const float* dhi = &dvs[(mb + 32) * STR];

    float acc0 = 0.0f, acc1 = 0.0f;
#pragma unroll 2
    for (int t = 0; t < 4; ++t) {
        const int n = w * 8 + t * 2 + h;
        const float* rec = &tabs[n * REC];
        const float x0 = dlo[n * 3 + 0], y0 = dlo[n * 3 + 1], z0 = dlo[n * 3 + 2];
        const float x1 = dhi[n * 3 + 0], y1 = dhi[n * 3 + 1], z1 = dhi[n * 3 + 2];

        const float r2a  = __fmaf_rn(x0, x0, __fmaf_rn(y0, y0, z0 * z0));
        const float r2b  = __fmaf_rn(x1, x1, __fmaf_rn(y1, y1, z1 * z1));
        const float ria  = __builtin_amdgcn_rsqf(r2a);
        const float rib  = __builtin_amdgcn_rsqf(r2b);
        const float ra   = r2a * ria;
        const float rb   = r2b * rib;
        const float la   = 0.5f * __builtin_amdgcn_logf(r2a);   // log2(r)
        const float lb   = 0.5f * __builtin_amdgcn_logf(r2b);
        const float ax = x0 * ria, ay = y0 * ria, az = z0 * ria;
        const float bx = x1 * rib, by = y1 * rib, bz = z1 * rib;

        const float4 h0 = *(const float4*)(rec);       // bc0,p0,bc1,p1
        const float2 h1 = *(const float2*)(rec + 4);   // bc2,p2
        float eka[3], ekb[3];
        eka[0] = __builtin_amdgcn_exp2f(__fmaf_rn(h0.y, la, -h0.x * ra));
        ekb[0] = __builtin_amdgcn_exp2f(__fmaf_rn(h0.y, lb, -h0.x * rb));
        eka[1] = __builtin_amdgcn_exp2f(__fmaf_rn(h0.w, la, -h0.z * ra));
        ekb[1] = __builtin_amdgcn_exp2f(__fmaf_rn(h0.w, lb, -h0.z * rb));
        eka[2] = __builtin_amdgcn_exp2f(__fmaf_rn(h1.y, la, -h1.x * ra));
        ekb[2] = __builtin_amdgcn_exp2f(__fmaf_rn(h1.y, lb, -h1.x * rb));
#pragma unroll
        for (int f = 0; f < Ff; ++f) {
            const float4 e = *(const float4*)(rec + 8 + f * 4);  // A, ux, uy, uz
            const float ca = __fmaf_rn(ax, e.y, __fmaf_rn(ay, e.z, az * e.w));
            const float cb = __fmaf_rn(bx, e.y, __fmaf_rn(by, e.z, bz * e.w));
            float qa, qb;
            if (f % 3 == 0)      { qa = ca;                               qb = cb; }
            else if (f % 3 == 1) { qa = __fmaf_rn(1.5f * ca, ca, -0.5f);  qb = __fmaf_rn(1.5f * cb, cb, -0.5f); }
            else                 { qa = ca * __fmaf_rn(2.5f * ca, ca, -1.5f);
                                   qb = cb * __fmaf_rn(2.5f * cb, cb, -1.5f); }
            acc0 = __fmaf_rn(e.x * eka[f / 3], qa, acc0);
            acc1 = __fmaf_rn(e.x * ekb[f / 3], qb, acc1);
        }
    }

    // ---- reduce: halves within wave, then 8 waves via LDS ----
    acc0 += __shfl_down(acc0, 32, 64);
    acc1 += __shfl_down(acc1, 32, 64);
    if (h == 0) {
        red[w * 64 + mb]      = acc0;   // m = mb
        red[w * 64 + 32 + mb] = acc1;   // m = mb + 32
    }
    __syncthreads();
    if (tid < MT) {
        float s = 0.0f;
#pragma unroll
        for (int w2 = 0; w2 < 8; ++w2) s += red[w2 * 64 + tid];
        out[(size_t)b * Mm + m0 + tid] = s;
    }
}

extern "C" void kernel_launch(void* const* d_in, const int* in_sizes, int n_in,
                              void* d_out, int out_size, void* d_ws, size_t ws_size,
                              hipStream_t stream) {
    const float* dv   = (const float*)d_in[0];
    const float* coef = (const float*)d_in[1];
    const int*   lab  = (const int*)d_in[2];
    const float* pa   = (const float*)d_in[3];
    const float* pb   = (const float*)d_in[4];
    const float* pp   = (const float*)d_in[5];
    float* out = (float*)d_out;

    dim3 grid(Bb * (Mm / MT));  // 512 blocks x 512 threads = 2 blk/CU, 16 waves/CU
    HarmonicGenAMD_25786983645325_kernel<<<grid, 512, 0, stream>>>(
        dv, coef, lab, pa, pb, pp, out);
}